// Round 1
// 1514.279 us; speedup vs baseline: 1.0563x; 1.0563x over previous
//
#include <hip/hip_runtime.h>
#include <math.h>

#define NN 100000
#define EE 1600000
#define SCAN_BLOCKS 98   // ceil(NN/1024)

typedef short s16x8 __attribute__((ext_vector_type(8)));
typedef float f32x4 __attribute__((ext_vector_type(4)));

union FragU { uint4 u; s16x8 s; };

__device__ __forceinline__ unsigned short f2bf(float x) {
    unsigned int u = __float_as_uint(x);
    u = (u + 0x7fff + ((u >> 16) & 1)) >> 16;   // round-to-nearest-even
    return (unsigned short)u;
}
__device__ __forceinline__ float bf2f(unsigned short b) {
    return __uint_as_float(((unsigned int)b) << 16);
}
__device__ __forceinline__ float bflo(unsigned int u) { return __uint_as_float(u << 16); }
__device__ __forceinline__ float bfhi(unsigned int u) { return __uint_as_float(u & 0xffff0000u); }

__device__ __forceinline__ void gload16(const unsigned short* g, unsigned short* l) {
    __builtin_amdgcn_global_load_lds(
        (const __attribute__((address_space(1))) unsigned int*)g,
        (__attribute__((address_space(3))) unsigned int*)l, 16, 0, 0);
}

// ---------------------------------------------------------------------------
// bf16 MFMA GEMM (m97 structure): BM=BN=128, BK=32, 256 thr = 4 waves (2x2),
// each wave a 64x64 tile = 4x4 MFMA 16x16x32. A = [A1 | A2] along K (row-major
// bf16, strides K1/K2). BT = B transposed [256][K1+K2] bf16. Staging via
// global_load_lds(16B), LDS unpadded in lane order.
// MODE 0: bf16 out (+optional bias bl). MODE 1: fp32 sigmoid(acc+bl+b2) out.
// ---------------------------------------------------------------------------
template<int K1, int K2, int MODE>
__global__ __launch_bounds__(256)
void gemm_mfma(const unsigned short* __restrict__ A1,
               const unsigned short* __restrict__ A2,
               const unsigned short* __restrict__ BT,
               const float* __restrict__ bl, const float* __restrict__ b2,
               void* __restrict__ Cout, int M)
{
    constexpr int KT = K1 + K2;
    __shared__ __align__(16) unsigned short As[128 * 32];
    __shared__ __align__(16) unsigned short Bs[128 * 32];

    const int tid  = threadIdx.x;
    const int w    = tid >> 6, lane = tid & 63;
    const int l15  = lane & 15, g = lane >> 4;
    const int m0   = blockIdx.x * 128;
    const int n0   = blockIdx.y * 128;
    const int wm   = (w >> 1) * 64, wn = (w & 1) * 64;

    f32x4 acc[4][4];
#pragma unroll
    for (int i = 0; i < 4; i++)
#pragma unroll
        for (int j = 0; j < 4; j++) { acc[i][j][0]=0.f; acc[i][j][1]=0.f; acc[i][j][2]=0.f; acc[i][j][3]=0.f; }

    for (int k0 = 0; k0 < KT; k0 += 32) {
        const unsigned short* Ap; int astr, kloc;
        if (K1 > 0 && k0 < K1) { Ap = A1; astr = K1; kloc = k0; }
        else                   { Ap = A2; astr = K2; kloc = k0 - K1; }

#pragma unroll
        for (int c = 0; c < 2; c++) {
            const int chunk = ((w * 2 + c) << 6) + lane;   // 16B chunk id in tile
            const int row = chunk >> 2, kc = chunk & 3;
            int rg = m0 + row; if (rg > M - 1) rg = M - 1;
            // LDS dest: wave-uniform base; HW scatters lane*16B
            gload16(Ap + (size_t)rg * astr + kloc + kc * 8, As + (w * 2 + c) * 512);
            gload16(BT + (size_t)(n0 + row) * KT + k0 + kc * 8, Bs + (w * 2 + c) * 512);
        }
        __syncthreads();   // drains vmcnt before LDS reads

        FragU a[4], b[4];
#pragma unroll
        for (int i = 0; i < 4; i++) {
            a[i].u = *(const uint4*)(As + (wm + i * 16 + l15) * 32 + g * 8);
            b[i].u = *(const uint4*)(Bs + (wn + i * 16 + l15) * 32 + g * 8);
        }
#pragma unroll
        for (int i = 0; i < 4; i++)
#pragma unroll
            for (int j = 0; j < 4; j++)
                acc[i][j] = __builtin_amdgcn_mfma_f32_16x16x32_bf16(a[i].s, b[j].s, acc[i][j], 0, 0, 0);
        __syncthreads();
    }

    // epilogue: C/D layout col=lane&15, row=(lane>>4)*4+reg (m89-verified)
    float badd[4];
#pragma unroll
    for (int j = 0; j < 4; j++) {
        const int col = n0 + wn + j * 16 + l15;
        badd[j] = bl ? bl[col] : 0.0f;
        if (MODE == 1) badd[j] += b2[col];
    }
#pragma unroll
    for (int i = 0; i < 4; i++) {
#pragma unroll
        for (int r = 0; r < 4; r++) {
            const int rowg = m0 + wm + i * 16 + g * 4 + r;
            if (rowg < M) {
#pragma unroll
                for (int j = 0; j < 4; j++) {
                    const int col = n0 + wn + j * 16 + l15;
                    float t = acc[i][j][r] + badd[j];
                    if (MODE == 1) {
                        t = 1.0f / (1.0f + __expf(-t));
                        ((float*)Cout)[(size_t)rowg * 256 + col] = t;
                    } else {
                        ((unsigned short*)Cout)[(size_t)rowg * 256 + col] = f2bf(t);
                    }
                }
            }
        }
    }
}

// ---------------------------------------------------------------------------
// CSR build: fused dual-edge-type histogram -> multi-block scan -> fill.
// rowptr laid out [2][NN+1]; work (atomically consumed copy) [2][NN].
// ---------------------------------------------------------------------------
__global__ __launch_bounds__(256)
void hist2_kernel(const int* __restrict__ dst_ba, const int* __restrict__ dst_ab,
                  int* __restrict__ cnt)
{
    const int e = blockIdx.x * 256 + threadIdx.x;
    const int y = blockIdx.y;
    if (e < EE) {
        const int d = (y == 0) ? dst_ba[e] : dst_ab[e];
        atomicAdd(&cnt[y * NN + d], 1);
    }
}

__device__ __forceinline__ int wave_incl_scan(int v, int lane)
{
#pragma unroll
    for (int off = 1; off < 64; off <<= 1) {
        int t = __shfl_up(v, off, 64);
        if (lane >= off) v += t;
    }
    return v;
}

// pass 1: per-block (1024-wide) local exclusive scan into rowptr, block sums out
__global__ __launch_bounds__(1024)
void scan_local_kernel(const int* __restrict__ cnt, int* __restrict__ rowptr,
                       int* __restrict__ bsum)
{
    __shared__ int wsum[16];
    __shared__ int wpre[16];
    const int y = blockIdx.y, b = blockIdx.x;
    const int tid = threadIdx.x, lane = tid & 63, wid = tid >> 6;
    const int i = b * 1024 + tid;
    const int v = (i < NN) ? cnt[y * NN + i] : 0;
    const int incl = wave_incl_scan(v, lane);
    if (lane == 63) wsum[wid] = incl;
    __syncthreads();
    if (wid == 0) {
        const int s  = (lane < 16) ? wsum[lane] : 0;
        const int si = wave_incl_scan(s, lane);
        if (lane < 16) wpre[lane] = si - s;
    }
    __syncthreads();
    const int excl = wpre[wid] + incl - v;
    if (i < NN) rowptr[y * (NN + 1) + i] = excl;
    if (tid == 1023) bsum[y * 128 + b] = excl + v;   // block total
}

// pass 2: scan the (<=128 per type) block sums; also writes rowptr[y][NN]=total
__global__ __launch_bounds__(256)
void scan_bsum_kernel(const int* __restrict__ bsum, int* __restrict__ boff,
                      int* __restrict__ rowptr)
{
    __shared__ int ws[2][2];
    const int tid = threadIdx.x;
    const int y = tid >> 7, j = tid & 127, lane = j & 63, wid = j >> 6;
    const int v = (j < SCAN_BLOCKS) ? bsum[y * 128 + j] : 0;
    const int incl = wave_incl_scan(v, lane);
    if (lane == 63) ws[y][wid] = incl;
    __syncthreads();
    const int off = (wid == 1) ? ws[y][0] : 0;
    boff[y * 128 + j] = off + incl - v;
    if (j == 127) rowptr[y * (NN + 1) + NN] = off + incl;
}

// pass 3: add block offsets in place; duplicate into atomically-consumed copy
__global__ __launch_bounds__(1024)
void scan_add_kernel(const int* __restrict__ boff, int* __restrict__ rowptr,
                     int* __restrict__ work)
{
    const int y = blockIdx.y, b = blockIdx.x;
    const int i = b * 1024 + threadIdx.x;
    if (i < NN) {
        const int r = rowptr[y * (NN + 1) + i] + boff[y * 128 + b];
        rowptr[y * (NN + 1) + i] = r;
        work[y * NN + i] = r;
    }
}

__global__ __launch_bounds__(256)
void fill2_kernel(const int* __restrict__ src_ba, const int* __restrict__ dst_ba,
                  const int* __restrict__ src_ab, const int* __restrict__ dst_ab,
                  int* __restrict__ work, int* __restrict__ ssrc)
{
    const int e = blockIdx.x * 256 + threadIdx.x;
    const int y = blockIdx.y;
    if (e < EE) {
        const int d = (y == 0) ? dst_ba[e] : dst_ab[e];
        const int s = (y == 0) ? src_ba[e] : src_ab[e];
        const int pos = atomicAdd(&work[y * NN + d], 1);
        ssrc[(size_t)y * EE + pos] = s;
    }
}

// ---------------------------------------------------------------------------
// bf16 gather-mean: one block (128 thr) per dst node.
// 32 lanes x 16B cover one 512B source row; 4 edge slots in flight.
// ---------------------------------------------------------------------------
__global__ __launch_bounds__(128)
void agg_bf(const unsigned short* __restrict__ feat, const int* __restrict__ rowptr,
            const int* __restrict__ ssrc, unsigned short* __restrict__ out)
{
    __shared__ float red[32][8];
    const int node = blockIdx.x;
    const int t = threadIdx.x;
    const int slot = t >> 5;        // 0..3 edge slot
    const int c = t & 31;           // 16B chunk -> channels 8c..8c+7
    const int beg = rowptr[node], end = rowptr[node + 1];
    const int deg = end - beg;

    float a0=0.f,a1=0.f,a2=0.f,a3=0.f,a4=0.f,a5=0.f,a6=0.f,a7=0.f;
    for (int i = beg + slot; i < end; i += 4) {
        const uint4 v = *(const uint4*)(feat + ((size_t)ssrc[i] << 8) + c * 8);
        a0 += bflo(v.x); a1 += bfhi(v.x);
        a2 += bflo(v.y); a3 += bfhi(v.y);
        a4 += bflo(v.z); a5 += bfhi(v.z);
        a6 += bflo(v.w); a7 += bfhi(v.w);
    }
    // slot pairs within each wave: lane l <-> l^32
    a0 += __shfl_xor(a0, 32, 64); a1 += __shfl_xor(a1, 32, 64);
    a2 += __shfl_xor(a2, 32, 64); a3 += __shfl_xor(a3, 32, 64);
    a4 += __shfl_xor(a4, 32, 64); a5 += __shfl_xor(a5, 32, 64);
    a6 += __shfl_xor(a6, 32, 64); a7 += __shfl_xor(a7, 32, 64);
    // cross-wave: wave1 lanes 0..31 (slots 2+3) -> LDS
    if (t >= 64 && t < 96) {
        red[c][0]=a0; red[c][1]=a1; red[c][2]=a2; red[c][3]=a3;
        red[c][4]=a4; red[c][5]=a5; red[c][6]=a6; red[c][7]=a7;
    }
    __syncthreads();
    if (t < 32) {
        a0 += red[c][0]; a1 += red[c][1]; a2 += red[c][2]; a3 += red[c][3];
        a4 += red[c][4]; a5 += red[c][5]; a6 += red[c][6]; a7 += red[c][7];
        const float inv = 1.0f / fmaxf((float)deg, 1.0f);
        uint4 o;
        o.x = (unsigned int)f2bf(a0 * inv) | ((unsigned int)f2bf(a1 * inv) << 16);
        o.y = (unsigned int)f2bf(a2 * inv) | ((unsigned int)f2bf(a3 * inv) << 16);
        o.z = (unsigned int)f2bf(a4 * inv) | ((unsigned int)f2bf(a5 * inv) << 16);
        o.w = (unsigned int)f2bf(a6 * inv) | ((unsigned int)f2bf(a7 * inv) << 16);
        *(uint4*)(out + ((size_t)node << 8) + c * 8) = o;
    }
}

// ---------------------------------------------------------------------------
// converts
// ---------------------------------------------------------------------------
__global__ __launch_bounds__(256)
void f2bf4_kernel(const float* __restrict__ in, unsigned short* __restrict__ out, int n4)
{
    const int i = blockIdx.x * 256 + threadIdx.x;
    if (i < n4) {
        const float4 v = ((const float4*)in)[i];
        ushort4 o;
        o.x = f2bf(v.x); o.y = f2bf(v.y); o.z = f2bf(v.z); o.w = f2bf(v.w);
        ((ushort4*)out)[i] = o;
    }
}

// W [K][256] fp32 -> WT [256][KT] bf16 at column offset koff
__global__ __launch_bounds__(256)
void wt_kernel(const float* __restrict__ W, unsigned short* __restrict__ WT,
               int K, int KT, int koff)
{
    const int idx = blockIdx.x * 256 + threadIdx.x;
    if (idx < K * 256) {
        const int k = idx >> 8, n = idx & 255;
        WT[(size_t)n * KT + koff + k] = f2bf(W[(size_t)k * 256 + n]);
    }
}

// ---------------------------------------------------------------------------
extern "C" void kernel_launch(void* const* d_in, const int* in_sizes, int n_in,
                              void* d_out, int out_size, void* d_ws, size_t ws_size,
                              hipStream_t stream)
{
    const float* x_A    = (const float*)d_in[0];
    const float* x_B    = (const float*)d_in[1];
    const int*   e_ab   = (const int*)d_in[4];
    const int*   e_ba   = (const int*)d_in[5];
    const float* lin_A  = (const float*)d_in[6];
    const float* lin_B  = (const float*)d_in[7];
    const float* bias_A = (const float*)d_in[8];
    const float* bias_B = (const float*)d_in[9];
    const float* Wl_ab0 = (const float*)d_in[10]; const float* bl_ab0 = (const float*)d_in[11]; const float* Wr_ab0 = (const float*)d_in[12];
    const float* Wl_ba0 = (const float*)d_in[13]; const float* bl_ba0 = (const float*)d_in[14]; const float* Wr_ba0 = (const float*)d_in[15];
    const float* Wl_ab1 = (const float*)d_in[16]; const float* bl_ab1 = (const float*)d_in[17]; const float* Wr_ab1 = (const float*)d_in[18];
    const float* Wl_ba1 = (const float*)d_in[19]; const float* bl_ba1 = (const float*)d_in[20]; const float* Wr_ba1 = (const float*)d_in[21];

    float* gA = (float*)d_out;
    float* gB = gA + (size_t)NN * 256;

    // ---- workspace carve (ushort units) ----
    const size_t HALF = (size_t)NN * 128;           // 12.8M
    const size_t FULL = (size_t)NN * 256;           // 25.6M
    unsigned short* xb    = (unsigned short*)d_ws;  // xbA|xbB; later l0A
    unsigned short* xbA   = xb;
    unsigned short* xbB   = xb + HALF;
    unsigned short* l0A   = xb;                     // reuse after proj GEMMs
    unsigned short* projA = xb + FULL;              // later l0B
    unsigned short* l0B   = projA;
    unsigned short* projB = projA + FULL;
    unsigned short* aggb  = projB + FULL;
    unsigned short* linAT = aggb + FULL;            // [256][128]
    unsigned short* linBT = linAT + 256 * 128;
    unsigned short* WTba0 = linBT + 256 * 128;      // [256][512] each
    unsigned short* WTab0 = WTba0 + 256 * 512;
    unsigned short* WTba1 = WTab0 + 256 * 512;
    unsigned short* WTab1 = WTba1 + 256 * 512;
    int* ssrc2   = (int*)(WTab1 + 256 * 512);       // [2][EE]  (0=ba, 1=ab)
    int* rowptr2 = ssrc2 + 2 * (size_t)EE;          // [2][NN+1]
    int* work2   = rowptr2 + 2 * (NN + 1);          // [2][NN]
    int* cnt2    = work2 + 2 * NN;                  // [2][NN]
    int* bsum    = cnt2 + 2 * NN;                   // [2][128]
    int* boff    = bsum + 2 * 128;                  // [2][128]

    int* ssrc_ba   = ssrc2;
    int* ssrc_ab   = ssrc2 + EE;
    int* rowptr_ba = rowptr2;
    int* rowptr_ab = rowptr2 + (NN + 1);

    const int* src_ab = e_ab;  const int* dst_ab = e_ab + EE;
    const int* src_ba = e_ba;  const int* dst_ba = e_ba + EE;

    const int gE = (EE + 255) / 256;
    const dim3 gg((NN + 127) / 128, 2);             // 782 x 2
    const dim3 gE2(gE, 2);
    const dim3 gScan(SCAN_BLOCKS, 2);

    // ---- CSR build (both edge types fused; multi-block scan) ----
    hipMemsetAsync(cnt2, 0, 2 * NN * sizeof(int), stream);
    hist2_kernel<<<gE2, 256, 0, stream>>>(dst_ba, dst_ab, cnt2);
    scan_local_kernel<<<gScan, 1024, 0, stream>>>(cnt2, rowptr2, bsum);
    scan_bsum_kernel<<<1, 256, 0, stream>>>(bsum, boff, rowptr2);
    scan_add_kernel<<<gScan, 1024, 0, stream>>>(boff, rowptr2, work2);
    fill2_kernel<<<gE2, 256, 0, stream>>>(src_ba, dst_ba, src_ab, dst_ab, work2, ssrc2);

    // ---- convert inputs & weights to bf16 (weights transposed) ----
    f2bf4_kernel<<<(int)(HALF / 4 + 255) / 256, 256, 0, stream>>>(x_A, xbA, (int)(HALF / 4));
    f2bf4_kernel<<<(int)(HALF / 4 + 255) / 256, 256, 0, stream>>>(x_B, xbB, (int)(HALF / 4));
    wt_kernel<<<128, 256, 0, stream>>>(lin_A, linAT, 128, 128, 0);
    wt_kernel<<<128, 256, 0, stream>>>(lin_B, linBT, 128, 128, 0);
    wt_kernel<<<256, 256, 0, stream>>>(Wl_ba0, WTba0, 256, 512, 0);
    wt_kernel<<<256, 256, 0, stream>>>(Wr_ba0, WTba0, 256, 512, 256);
    wt_kernel<<<256, 256, 0, stream>>>(Wl_ab0, WTab0, 256, 512, 0);
    wt_kernel<<<256, 256, 0, stream>>>(Wr_ab0, WTab0, 256, 512, 256);
    wt_kernel<<<256, 256, 0, stream>>>(Wl_ba1, WTba1, 256, 512, 0);
    wt_kernel<<<256, 256, 0, stream>>>(Wr_ba1, WTba1, 256, 512, 256);
    wt_kernel<<<256, 256, 0, stream>>>(Wl_ab1, WTab1, 256, 512, 0);
    wt_kernel<<<256, 256, 0, stream>>>(Wr_ab1, WTab1, 256, 512, 256);

    // ---- input projections (bf16 out) ----
    gemm_mfma<0, 128, 0><<<gg, 256, 0, stream>>>(nullptr, xbA, linAT, nullptr, nullptr, projA, NN);
    gemm_mfma<0, 128, 0><<<gg, 256, 0, stream>>>(nullptr, xbB, linBT, nullptr, nullptr, projB, NN);

    // ---- layer 0 ----
    agg_bf<<<NN, 128, 0, stream>>>(projB, rowptr_ba, ssrc_ba, aggb);          // mean B->A
    gemm_mfma<256, 256, 0><<<gg, 256, 0, stream>>>(aggb, projA, WTba0, bl_ba0, nullptr, l0A, NN);
    agg_bf<<<NN, 128, 0, stream>>>(projA, rowptr_ab, ssrc_ab, aggb);          // mean A->B
    gemm_mfma<256, 256, 0><<<gg, 256, 0, stream>>>(aggb, projB, WTab0, bl_ab0, nullptr, l0B, NN);

    // ---- layer 1 (final: fp32 + per-type bias + sigmoid into d_out) ----
    agg_bf<<<NN, 128, 0, stream>>>(l0B, rowptr_ba, ssrc_ba, aggb);            // mean B->A
    gemm_mfma<256, 256, 1><<<gg, 256, 0, stream>>>(aggb, l0A, WTba1, bl_ba1, bias_A, gA, NN);
    agg_bf<<<NN, 128, 0, stream>>>(l0A, rowptr_ab, ssrc_ab, aggb);            // mean A->B
    gemm_mfma<256, 256, 1><<<gg, 256, 0, stream>>>(aggb, l0B, WTab1, bl_ab1, bias_B, gB, NN);
}

// Round 2
// 1357.519 us; speedup vs baseline: 1.1783x; 1.1155x over previous
//
#include <hip/hip_runtime.h>
#include <math.h>

#define NN 100000
#define EE 1600000
#define SCAN_BLOCKS 98   // ceil(NN/1024)

typedef short s16x8 __attribute__((ext_vector_type(8)));
typedef float f32x4 __attribute__((ext_vector_type(4)));

union FragU { uint4 u; s16x8 s; };

__device__ __forceinline__ unsigned short f2bf(float x) {
    unsigned int u = __float_as_uint(x);
    u = (u + 0x7fff + ((u >> 16) & 1)) >> 16;   // round-to-nearest-even
    return (unsigned short)u;
}
__device__ __forceinline__ float bf2f(unsigned short b) {
    return __uint_as_float(((unsigned int)b) << 16);
}
__device__ __forceinline__ float bflo(unsigned int u) { return __uint_as_float(u << 16); }
__device__ __forceinline__ float bfhi(unsigned int u) { return __uint_as_float(u & 0xffff0000u); }

__device__ __forceinline__ void gload16(const unsigned short* g, unsigned short* l) {
    __builtin_amdgcn_global_load_lds(
        (const __attribute__((address_space(1))) unsigned int*)g,
        (__attribute__((address_space(3))) unsigned int*)l, 16, 0, 0);
}

// ---------------------------------------------------------------------------
// bf16 MFMA GEMM (m97 structure): BM=BN=128, BK=32, 256 thr = 4 waves (2x2),
// each wave a 64x64 tile = 4x4 MFMA 16x16x32. A = [A1 | A2] along K (row-major
// bf16, strides K1/K2). BT = B transposed [256][K1+K2] bf16. Staging via
// global_load_lds(16B), LDS unpadded in lane order.
// MODE 0: bf16 out (+optional bias bl). MODE 1: fp32 sigmoid(acc+bl+b2) out.
// ---------------------------------------------------------------------------
template<int K1, int K2, int MODE>
__global__ __launch_bounds__(256)
void gemm_mfma(const unsigned short* __restrict__ A1,
               const unsigned short* __restrict__ A2,
               const unsigned short* __restrict__ BT,
               const float* __restrict__ bl, const float* __restrict__ b2,
               void* __restrict__ Cout, int M)
{
    constexpr int KT = K1 + K2;
    __shared__ __align__(16) unsigned short As[128 * 32];
    __shared__ __align__(16) unsigned short Bs[128 * 32];

    const int tid  = threadIdx.x;
    const int w    = tid >> 6, lane = tid & 63;
    const int l15  = lane & 15, g = lane >> 4;
    const int m0   = blockIdx.x * 128;
    const int n0   = blockIdx.y * 128;
    const int wm   = (w >> 1) * 64, wn = (w & 1) * 64;

    f32x4 acc[4][4];
#pragma unroll
    for (int i = 0; i < 4; i++)
#pragma unroll
        for (int j = 0; j < 4; j++) { acc[i][j][0]=0.f; acc[i][j][1]=0.f; acc[i][j][2]=0.f; acc[i][j][3]=0.f; }

    for (int k0 = 0; k0 < KT; k0 += 32) {
        const unsigned short* Ap; int astr, kloc;
        if (K1 > 0 && k0 < K1) { Ap = A1; astr = K1; kloc = k0; }
        else                   { Ap = A2; astr = K2; kloc = k0 - K1; }

#pragma unroll
        for (int c = 0; c < 2; c++) {
            const int chunk = ((w * 2 + c) << 6) + lane;   // 16B chunk id in tile
            const int row = chunk >> 2, kc = chunk & 3;
            int rg = m0 + row; if (rg > M - 1) rg = M - 1;
            // LDS dest: wave-uniform base; HW scatters lane*16B
            gload16(Ap + (size_t)rg * astr + kloc + kc * 8, As + (w * 2 + c) * 512);
            gload16(BT + (size_t)(n0 + row) * KT + k0 + kc * 8, Bs + (w * 2 + c) * 512);
        }
        __syncthreads();   // drains vmcnt before LDS reads

        FragU a[4], b[4];
#pragma unroll
        for (int i = 0; i < 4; i++) {
            a[i].u = *(const uint4*)(As + (wm + i * 16 + l15) * 32 + g * 8);
            b[i].u = *(const uint4*)(Bs + (wn + i * 16 + l15) * 32 + g * 8);
        }
#pragma unroll
        for (int i = 0; i < 4; i++)
#pragma unroll
            for (int j = 0; j < 4; j++)
                acc[i][j] = __builtin_amdgcn_mfma_f32_16x16x32_bf16(a[i].s, b[j].s, acc[i][j], 0, 0, 0);
        __syncthreads();
    }

    // epilogue: C/D layout col=lane&15, row=(lane>>4)*4+reg (m89-verified)
    float badd[4];
#pragma unroll
    for (int j = 0; j < 4; j++) {
        const int col = n0 + wn + j * 16 + l15;
        badd[j] = bl ? bl[col] : 0.0f;
        if (MODE == 1) badd[j] += b2[col];
    }
#pragma unroll
    for (int i = 0; i < 4; i++) {
#pragma unroll
        for (int r = 0; r < 4; r++) {
            const int rowg = m0 + wm + i * 16 + g * 4 + r;
            if (rowg < M) {
#pragma unroll
                for (int j = 0; j < 4; j++) {
                    const int col = n0 + wn + j * 16 + l15;
                    float t = acc[i][j][r] + badd[j];
                    if (MODE == 1) {
                        t = 1.0f / (1.0f + __expf(-t));
                        ((float*)Cout)[(size_t)rowg * 256 + col] = t;
                    } else {
                        ((unsigned short*)Cout)[(size_t)rowg * 256 + col] = f2bf(t);
                    }
                }
            }
        }
    }
}

// ---------------------------------------------------------------------------
// CSR build: histogram+rank -> multi-block scan -> rank-addressed fill.
// rowptr laid out [2][NN+1]; rank [2][EE] (aliased onto aggb region).
// ---------------------------------------------------------------------------
__global__ __launch_bounds__(256)
void histrank_kernel(const int* __restrict__ dst_ba, const int* __restrict__ dst_ab,
                     int* __restrict__ cnt, int* __restrict__ rank)
{
    const int e = blockIdx.x * 256 + threadIdx.x;
    const int y = blockIdx.y;
    if (e < EE) {
        const int d = (y == 0) ? dst_ba[e] : dst_ab[e];
        const int r = atomicAdd(&cnt[y * NN + d], 1);     // rank within dst row
        __builtin_nontemporal_store(r, &rank[(size_t)y * EE + e]);  // coalesced
    }
}

__device__ __forceinline__ int wave_incl_scan(int v, int lane)
{
#pragma unroll
    for (int off = 1; off < 64; off <<= 1) {
        int t = __shfl_up(v, off, 64);
        if (lane >= off) v += t;
    }
    return v;
}

// pass 1: per-block (1024-wide) local exclusive scan into rowptr, block sums out
__global__ __launch_bounds__(1024)
void scan_local_kernel(const int* __restrict__ cnt, int* __restrict__ rowptr,
                       int* __restrict__ bsum)
{
    __shared__ int wsum[16];
    __shared__ int wpre[16];
    const int y = blockIdx.y, b = blockIdx.x;
    const int tid = threadIdx.x, lane = tid & 63, wid = tid >> 6;
    const int i = b * 1024 + tid;
    const int v = (i < NN) ? cnt[y * NN + i] : 0;
    const int incl = wave_incl_scan(v, lane);
    if (lane == 63) wsum[wid] = incl;
    __syncthreads();
    if (wid == 0) {
        const int s  = (lane < 16) ? wsum[lane] : 0;
        const int si = wave_incl_scan(s, lane);
        if (lane < 16) wpre[lane] = si - s;
    }
    __syncthreads();
    const int excl = wpre[wid] + incl - v;
    if (i < NN) rowptr[y * (NN + 1) + i] = excl;
    if (tid == 1023) bsum[y * 128 + b] = excl + v;   // block total
}

// pass 2: scan the (<=128 per type) block sums; also writes rowptr[y][NN]=total
__global__ __launch_bounds__(256)
void scan_bsum_kernel(const int* __restrict__ bsum, int* __restrict__ boff,
                      int* __restrict__ rowptr)
{
    __shared__ int ws[2][2];
    const int tid = threadIdx.x;
    const int y = tid >> 7, j = tid & 127, lane = j & 63, wid = j >> 6;
    const int v = (j < SCAN_BLOCKS) ? bsum[y * 128 + j] : 0;
    const int incl = wave_incl_scan(v, lane);
    if (lane == 63) ws[y][wid] = incl;
    __syncthreads();
    const int off = (wid == 1) ? ws[y][0] : 0;
    boff[y * 128 + j] = off + incl - v;
    if (j == 127) rowptr[y * (NN + 1) + NN] = off + incl;
}

// pass 3: add block offsets in place
__global__ __launch_bounds__(1024)
void scan_add_kernel(const int* __restrict__ boff, int* __restrict__ rowptr)
{
    const int y = blockIdx.y, b = blockIdx.x;
    const int i = b * 1024 + threadIdx.x;
    if (i < NN) rowptr[y * (NN + 1) + i] += boff[y * 128 + b];
}

// fill: pure scattered store, no atomics, no dependency round-trip
__global__ __launch_bounds__(256)
void fillr_kernel(const int* __restrict__ src_ba, const int* __restrict__ dst_ba,
                  const int* __restrict__ src_ab, const int* __restrict__ dst_ab,
                  const int* __restrict__ rowptr, const int* __restrict__ rank,
                  int* __restrict__ ssrc)
{
    const int e = blockIdx.x * 256 + threadIdx.x;
    const int y = blockIdx.y;
    if (e < EE) {
        const int d = (y == 0) ? dst_ba[e] : dst_ab[e];
        const int s = (y == 0) ? src_ba[e] : src_ab[e];
        const int pos = rowptr[y * (NN + 1) + d] + rank[(size_t)y * EE + e];
        __builtin_nontemporal_store(s, &ssrc[(size_t)y * EE + pos]);
    }
}

// ---------------------------------------------------------------------------
// bf16 gather-mean: one block (128 thr) per dst node.
// 32 lanes x 16B cover one 512B source row; 4 edge slots in flight.
// ---------------------------------------------------------------------------
__global__ __launch_bounds__(128)
void agg_bf(const unsigned short* __restrict__ feat, const int* __restrict__ rowptr,
            const int* __restrict__ ssrc, unsigned short* __restrict__ out)
{
    __shared__ float red[32][8];
    const int node = blockIdx.x;
    const int t = threadIdx.x;
    const int slot = t >> 5;        // 0..3 edge slot
    const int c = t & 31;           // 16B chunk -> channels 8c..8c+7
    const int beg = rowptr[node], end = rowptr[node + 1];
    const int deg = end - beg;

    float a0=0.f,a1=0.f,a2=0.f,a3=0.f,a4=0.f,a5=0.f,a6=0.f,a7=0.f;
    for (int i = beg + slot; i < end; i += 4) {
        const uint4 v = *(const uint4*)(feat + ((size_t)ssrc[i] << 8) + c * 8);
        a0 += bflo(v.x); a1 += bfhi(v.x);
        a2 += bflo(v.y); a3 += bfhi(v.y);
        a4 += bflo(v.z); a5 += bfhi(v.z);
        a6 += bflo(v.w); a7 += bfhi(v.w);
    }
    // slot pairs within each wave: lane l <-> l^32
    a0 += __shfl_xor(a0, 32, 64); a1 += __shfl_xor(a1, 32, 64);
    a2 += __shfl_xor(a2, 32, 64); a3 += __shfl_xor(a3, 32, 64);
    a4 += __shfl_xor(a4, 32, 64); a5 += __shfl_xor(a5, 32, 64);
    a6 += __shfl_xor(a6, 32, 64); a7 += __shfl_xor(a7, 32, 64);
    // cross-wave: wave1 lanes 0..31 (slots 2+3) -> LDS
    if (t >= 64 && t < 96) {
        red[c][0]=a0; red[c][1]=a1; red[c][2]=a2; red[c][3]=a3;
        red[c][4]=a4; red[c][5]=a5; red[c][6]=a6; red[c][7]=a7;
    }
    __syncthreads();
    if (t < 32) {
        a0 += red[c][0]; a1 += red[c][1]; a2 += red[c][2]; a3 += red[c][3];
        a4 += red[c][4]; a5 += red[c][5]; a6 += red[c][6]; a7 += red[c][7];
        const float inv = 1.0f / fmaxf((float)deg, 1.0f);
        uint4 o;
        o.x = (unsigned int)f2bf(a0 * inv) | ((unsigned int)f2bf(a1 * inv) << 16);
        o.y = (unsigned int)f2bf(a2 * inv) | ((unsigned int)f2bf(a3 * inv) << 16);
        o.z = (unsigned int)f2bf(a4 * inv) | ((unsigned int)f2bf(a5 * inv) << 16);
        o.w = (unsigned int)f2bf(a6 * inv) | ((unsigned int)f2bf(a7 * inv) << 16);
        *(uint4*)(out + ((size_t)node << 8) + c * 8) = o;
    }
}

// ---------------------------------------------------------------------------
// converts
// ---------------------------------------------------------------------------
__global__ __launch_bounds__(256)
void f2bf4_kernel(const float* __restrict__ in, unsigned short* __restrict__ out, int n4)
{
    const int i = blockIdx.x * 256 + threadIdx.x;
    if (i < n4) {
        const float4 v = ((const float4*)in)[i];
        ushort4 o;
        o.x = f2bf(v.x); o.y = f2bf(v.y); o.z = f2bf(v.z); o.w = f2bf(v.w);
        ((ushort4*)out)[i] = o;
    }
}

// W [K][256] fp32 -> WT [256][KT] bf16 at column offset koff
__global__ __launch_bounds__(256)
void wt_kernel(const float* __restrict__ W, unsigned short* __restrict__ WT,
               int K, int KT, int koff)
{
    const int idx = blockIdx.x * 256 + threadIdx.x;
    if (idx < K * 256) {
        const int k = idx >> 8, n = idx & 255;
        WT[(size_t)n * KT + koff + k] = f2bf(W[(size_t)k * 256 + n]);
    }
}

// ---------------------------------------------------------------------------
extern "C" void kernel_launch(void* const* d_in, const int* in_sizes, int n_in,
                              void* d_out, int out_size, void* d_ws, size_t ws_size,
                              hipStream_t stream)
{
    const float* x_A    = (const float*)d_in[0];
    const float* x_B    = (const float*)d_in[1];
    const int*   e_ab   = (const int*)d_in[4];
    const int*   e_ba   = (const int*)d_in[5];
    const float* lin_A  = (const float*)d_in[6];
    const float* lin_B  = (const float*)d_in[7];
    const float* bias_A = (const float*)d_in[8];
    const float* bias_B = (const float*)d_in[9];
    const float* Wl_ab0 = (const float*)d_in[10]; const float* bl_ab0 = (const float*)d_in[11]; const float* Wr_ab0 = (const float*)d_in[12];
    const float* Wl_ba0 = (const float*)d_in[13]; const float* bl_ba0 = (const float*)d_in[14]; const float* Wr_ba0 = (const float*)d_in[15];
    const float* Wl_ab1 = (const float*)d_in[16]; const float* bl_ab1 = (const float*)d_in[17]; const float* Wr_ab1 = (const float*)d_in[18];
    const float* Wl_ba1 = (const float*)d_in[19]; const float* bl_ba1 = (const float*)d_in[20]; const float* Wr_ba1 = (const float*)d_in[21];

    float* gA = (float*)d_out;
    float* gB = gA + (size_t)NN * 256;

    // ---- workspace carve (ushort units) ----
    const size_t HALF = (size_t)NN * 128;           // 12.8M
    const size_t FULL = (size_t)NN * 256;           // 25.6M
    unsigned short* xb    = (unsigned short*)d_ws;  // xbA|xbB; later l0A
    unsigned short* xbA   = xb;
    unsigned short* xbB   = xb + HALF;
    unsigned short* l0A   = xb;                     // reuse after proj GEMMs
    unsigned short* projA = xb + FULL;              // later l0B
    unsigned short* l0B   = projA;
    unsigned short* projB = projA + FULL;
    unsigned short* aggb  = projB + FULL;
    unsigned short* linAT = aggb + FULL;            // [256][128]
    unsigned short* linBT = linAT + 256 * 128;
    unsigned short* WTba0 = linBT + 256 * 128;      // [256][512] each
    unsigned short* WTab0 = WTba0 + 256 * 512;
    unsigned short* WTba1 = WTab0 + 256 * 512;
    unsigned short* WTab1 = WTba1 + 256 * 512;
    int* ssrc2   = (int*)(WTab1 + 256 * 512);       // [2][EE]  (0=ba, 1=ab)
    int* rowptr2 = ssrc2 + 2 * (size_t)EE;          // [2][NN+1]
    int* cnt2    = rowptr2 + 2 * (NN + 1);          // [2][NN]
    int* bsum    = cnt2 + 2 * NN;                   // [2][128]
    int* boff    = bsum + 2 * 128;                  // [2][128]
    int* rank2   = (int*)aggb;                      // [2][EE], dead before aggs run

    int* ssrc_ba   = ssrc2;
    int* ssrc_ab   = ssrc2 + EE;
    int* rowptr_ba = rowptr2;
    int* rowptr_ab = rowptr2 + (NN + 1);

    const int* src_ab = e_ab;  const int* dst_ab = e_ab + EE;
    const int* src_ba = e_ba;  const int* dst_ba = e_ba + EE;

    const int gE = (EE + 255) / 256;
    const dim3 gg((NN + 127) / 128, 2);             // 782 x 2
    const dim3 gE2(gE, 2);
    const dim3 gScan(SCAN_BLOCKS, 2);

    // ---- CSR build (rank-addressed; no atomics in fill) ----
    hipMemsetAsync(cnt2, 0, 2 * NN * sizeof(int), stream);
    histrank_kernel<<<gE2, 256, 0, stream>>>(dst_ba, dst_ab, cnt2, rank2);
    scan_local_kernel<<<gScan, 1024, 0, stream>>>(cnt2, rowptr2, bsum);
    scan_bsum_kernel<<<1, 256, 0, stream>>>(bsum, boff, rowptr2);
    scan_add_kernel<<<gScan, 1024, 0, stream>>>(boff, rowptr2);
    fillr_kernel<<<gE2, 256, 0, stream>>>(src_ba, dst_ba, src_ab, dst_ab, rowptr2, rank2, ssrc2);

    // ---- convert inputs & weights to bf16 (weights transposed) ----
    f2bf4_kernel<<<(int)(HALF / 4 + 255) / 256, 256, 0, stream>>>(x_A, xbA, (int)(HALF / 4));
    f2bf4_kernel<<<(int)(HALF / 4 + 255) / 256, 256, 0, stream>>>(x_B, xbB, (int)(HALF / 4));
    wt_kernel<<<128, 256, 0, stream>>>(lin_A, linAT, 128, 128, 0);
    wt_kernel<<<128, 256, 0, stream>>>(lin_B, linBT, 128, 128, 0);
    wt_kernel<<<256, 256, 0, stream>>>(Wl_ba0, WTba0, 256, 512, 0);
    wt_kernel<<<256, 256, 0, stream>>>(Wr_ba0, WTba0, 256, 512, 256);
    wt_kernel<<<256, 256, 0, stream>>>(Wl_ab0, WTab0, 256, 512, 0);
    wt_kernel<<<256, 256, 0, stream>>>(Wr_ab0, WTab0, 256, 512, 256);
    wt_kernel<<<256, 256, 0, stream>>>(Wl_ba1, WTba1, 256, 512, 0);
    wt_kernel<<<256, 256, 0, stream>>>(Wr_ba1, WTba1, 256, 512, 256);
    wt_kernel<<<256, 256, 0, stream>>>(Wl_ab1, WTab1, 256, 512, 0);
    wt_kernel<<<256, 256, 0, stream>>>(Wr_ab1, WTab1, 256, 512, 256);

    // ---- input projections (bf16 out) ----
    gemm_mfma<0, 128, 0><<<gg, 256, 0, stream>>>(nullptr, xbA, linAT, nullptr, nullptr, projA, NN);
    gemm_mfma<0, 128, 0><<<gg, 256, 0, stream>>>(nullptr, xbB, linBT, nullptr, nullptr, projB, NN);

    // ---- layer 0 ----
    agg_bf<<<NN, 128, 0, stream>>>(projB, rowptr_ba, ssrc_ba, aggb);          // mean B->A
    gemm_mfma<256, 256, 0><<<gg, 256, 0, stream>>>(aggb, projA, WTba0, bl_ba0, nullptr, l0A, NN);
    agg_bf<<<NN, 128, 0, stream>>>(projA, rowptr_ab, ssrc_ab, aggb);          // mean A->B
    gemm_mfma<256, 256, 0><<<gg, 256, 0, stream>>>(aggb, projB, WTab0, bl_ab0, nullptr, l0B, NN);

    // ---- layer 1 (final: fp32 + per-type bias + sigmoid into d_out) ----
    agg_bf<<<NN, 128, 0, stream>>>(l0B, rowptr_ba, ssrc_ba, aggb);            // mean B->A
    gemm_mfma<256, 256, 1><<<gg, 256, 0, stream>>>(aggb, l0A, WTba1, bl_ba1, bias_A, gA, NN);
    agg_bf<<<NN, 128, 0, stream>>>(l0A, rowptr_ab, ssrc_ab, aggb);            // mean A->B
    gemm_mfma<256, 256, 1><<<gg, 256, 0, stream>>>(aggb, l0B, WTab1, bl_ab1, bias_B, gB, NN);
}

// Round 3
// 1299.937 us; speedup vs baseline: 1.2305x; 1.0443x over previous
//
#include <hip/hip_runtime.h>
#include <math.h>

#define NN 100000
#define EE 1600000
#define NBU 782          // coarse buckets = ceil(NN/128)
#define NCH 196          // edge chunks  = ceil(EE/8192)
#define CHUNK 8192

typedef short s16x8 __attribute__((ext_vector_type(8)));
typedef float f32x4 __attribute__((ext_vector_type(4)));

union FragU { uint4 u; s16x8 s; };

__device__ __forceinline__ unsigned short f2bf(float x) {
    unsigned int u = __float_as_uint(x);
    u = (u + 0x7fff + ((u >> 16) & 1)) >> 16;   // round-to-nearest-even
    return (unsigned short)u;
}
__device__ __forceinline__ float bf2f(unsigned short b) {
    return __uint_as_float(((unsigned int)b) << 16);
}
__device__ __forceinline__ float bflo(unsigned int u) { return __uint_as_float(u << 16); }
__device__ __forceinline__ float bfhi(unsigned int u) { return __uint_as_float(u & 0xffff0000u); }

__device__ __forceinline__ void gload16(const unsigned short* g, unsigned short* l) {
    __builtin_amdgcn_global_load_lds(
        (const __attribute__((address_space(1))) unsigned int*)g,
        (__attribute__((address_space(3))) unsigned int*)l, 16, 0, 0);
}

// ---------------------------------------------------------------------------
// bf16 MFMA GEMM (m97 structure): BM=BN=128, BK=32, 256 thr = 4 waves (2x2),
// each wave a 64x64 tile = 4x4 MFMA 16x16x32. A = [A1 | A2] along K (row-major
// bf16, strides K1/K2). BT = B transposed [256][K1+K2] bf16. Staging via
// global_load_lds(16B), LDS unpadded in lane order.
// MODE 0: bf16 out (+optional bias bl). MODE 1: fp32 sigmoid(acc+bl+b2) out.
// ---------------------------------------------------------------------------
template<int K1, int K2, int MODE>
__global__ __launch_bounds__(256)
void gemm_mfma(const unsigned short* __restrict__ A1,
               const unsigned short* __restrict__ A2,
               const unsigned short* __restrict__ BT,
               const float* __restrict__ bl, const float* __restrict__ b2,
               void* __restrict__ Cout, int M)
{
    constexpr int KT = K1 + K2;
    __shared__ __align__(16) unsigned short As[128 * 32];
    __shared__ __align__(16) unsigned short Bs[128 * 32];

    const int tid  = threadIdx.x;
    const int w    = tid >> 6, lane = tid & 63;
    const int l15  = lane & 15, g = lane >> 4;
    const int m0   = blockIdx.x * 128;
    const int n0   = blockIdx.y * 128;
    const int wm   = (w >> 1) * 64, wn = (w & 1) * 64;

    f32x4 acc[4][4];
#pragma unroll
    for (int i = 0; i < 4; i++)
#pragma unroll
        for (int j = 0; j < 4; j++) { acc[i][j][0]=0.f; acc[i][j][1]=0.f; acc[i][j][2]=0.f; acc[i][j][3]=0.f; }

    for (int k0 = 0; k0 < KT; k0 += 32) {
        const unsigned short* Ap; int astr, kloc;
        if (K1 > 0 && k0 < K1) { Ap = A1; astr = K1; kloc = k0; }
        else                   { Ap = A2; astr = K2; kloc = k0 - K1; }

#pragma unroll
        for (int c = 0; c < 2; c++) {
            const int chunk = ((w * 2 + c) << 6) + lane;   // 16B chunk id in tile
            const int row = chunk >> 2, kc = chunk & 3;
            int rg = m0 + row; if (rg > M - 1) rg = M - 1;
            // LDS dest: wave-uniform base; HW scatters lane*16B
            gload16(Ap + (size_t)rg * astr + kloc + kc * 8, As + (w * 2 + c) * 512);
            gload16(BT + (size_t)(n0 + row) * KT + k0 + kc * 8, Bs + (w * 2 + c) * 512);
        }
        __syncthreads();   // drains vmcnt before LDS reads

        FragU a[4], b[4];
#pragma unroll
        for (int i = 0; i < 4; i++) {
            a[i].u = *(const uint4*)(As + (wm + i * 16 + l15) * 32 + g * 8);
            b[i].u = *(const uint4*)(Bs + (wn + i * 16 + l15) * 32 + g * 8);
        }
#pragma unroll
        for (int i = 0; i < 4; i++)
#pragma unroll
            for (int j = 0; j < 4; j++)
                acc[i][j] = __builtin_amdgcn_mfma_f32_16x16x32_bf16(a[i].s, b[j].s, acc[i][j], 0, 0, 0);
        __syncthreads();
    }

    // epilogue: C/D layout col=lane&15, row=(lane>>4)*4+reg (m89-verified)
    float badd[4];
#pragma unroll
    for (int j = 0; j < 4; j++) {
        const int col = n0 + wn + j * 16 + l15;
        badd[j] = bl ? bl[col] : 0.0f;
        if (MODE == 1) badd[j] += b2[col];
    }
#pragma unroll
    for (int i = 0; i < 4; i++) {
#pragma unroll
        for (int r = 0; r < 4; r++) {
            const int rowg = m0 + wm + i * 16 + g * 4 + r;
            if (rowg < M) {
#pragma unroll
                for (int j = 0; j < 4; j++) {
                    const int col = n0 + wn + j * 16 + l15;
                    float t = acc[i][j][r] + badd[j];
                    if (MODE == 1) {
                        t = 1.0f / (1.0f + __expf(-t));
                        ((float*)Cout)[(size_t)rowg * 256 + col] = t;
                    } else {
                        ((unsigned short*)Cout)[(size_t)rowg * 256 + col] = f2bf(t);
                    }
                }
            }
        }
    }
}

__device__ __forceinline__ int wave_incl_scan(int v, int lane)
{
#pragma unroll
    for (int off = 1; off < 64; off <<= 1) {
        int t = __shfl_up(v, off, 64);
        if (lane >= off) v += t;
    }
    return v;
}

// ---------------------------------------------------------------------------
// Bucketed CSR build: all random access in LDS; global traffic coalesced.
// Coarse bucket = dst>>7 (128 nodes). Stage word = (src<<7)|(dst&127).
// ---------------------------------------------------------------------------
// P1: per-chunk coarse histogram (LDS), coalesced dump to cnt[y][chunk][NBU]
__global__ __launch_bounds__(256)
void p1_count(const int* __restrict__ dba, const int* __restrict__ dab,
              int* __restrict__ cnt)
{
    __shared__ int h[NBU];
    const int y = blockIdx.y, b = blockIdx.x;
    for (int i = threadIdx.x; i < NBU; i += 256) h[i] = 0;
    __syncthreads();
    const int* D = y ? dab : dba;
    const int base = b * CHUNK;
    for (int i = threadIdx.x; i < CHUNK; i += 256) {
        const int e = base + i;
        if (e < EE) atomicAdd(&h[D[e] >> 7], 1);
    }
    __syncthreads();
    for (int i = threadIdx.x; i < NBU; i += 256)
        cnt[(y * NCH + b) * NBU + i] = h[i];
}

// P2: bucket totals + exclusive scan -> baseG[y][NBU+1] (last entry = EE)
__global__ __launch_bounds__(1024)
void p2_scan(const int* __restrict__ cnt, int* __restrict__ baseG)
{
    __shared__ int tot[2 * NBU];
    const int tid = threadIdx.x;
    for (int i = tid; i < 2 * NBU; i += 1024) {
        const int y = i / NBU, u = i - y * NBU;
        int s = 0;
#pragma unroll 4
        for (int b = 0; b < NCH; b++) s += cnt[(y * NCH + b) * NBU + u];
        tot[i] = s;
    }
    __syncthreads();
    const int lane = tid & 63, wid = tid >> 6;
    if (wid < 2) {
        int run = 0;
        for (int c = 0; c < NBU; c += 64) {
            const int ui = c + lane;
            const int v = (ui < NBU) ? tot[wid * NBU + ui] : 0;
            const int incl = wave_incl_scan(v, lane);
            if (ui < NBU) baseG[wid * (NBU + 1) + ui] = run + incl - v;
            run += __shfl(incl, 63, 64);
        }
        if (lane == 0) baseG[wid * (NBU + 1) + NBU] = run;   // == EE
    }
}

// P2b: per-(chunk,bucket) scatter offsets
__global__ __launch_bounds__(256)
void p2b_off(const int* __restrict__ cnt, const int* __restrict__ baseG,
             int* __restrict__ blockOff)
{
    const int i = blockIdx.x * 256 + threadIdx.x;
    if (i >= 2 * NBU) return;
    const int y = i / NBU, u = i - y * NBU;
    int run = baseG[y * (NBU + 1) + u];
#pragma unroll 4
    for (int b = 0; b < NCH; b++) {
        blockOff[(y * NCH + b) * NBU + u] = run;
        run += cnt[(y * NCH + b) * NBU + u];
    }
}

// P3: scatter packed edges into bucket-contiguous staging (LDS cursors)
__global__ __launch_bounds__(256)
void p3_scatter(const int* __restrict__ sba, const int* __restrict__ dba,
                const int* __restrict__ sab, const int* __restrict__ dab,
                const int* __restrict__ blockOff, int* __restrict__ stage)
{
    __shared__ int cur[NBU];
    const int y = blockIdx.y, b = blockIdx.x;
    for (int i = threadIdx.x; i < NBU; i += 256)
        cur[i] = blockOff[(y * NCH + b) * NBU + i];
    __syncthreads();
    const int* S = y ? sab : sba;
    const int* D = y ? dab : dba;
    int* st = stage + (size_t)y * EE;
    const int base = b * CHUNK;
    for (int i = threadIdx.x; i < CHUNK; i += 256) {
        const int e = base + i;
        if (e < EE) {
            const int d = D[e], s = S[e];
            const int p = atomicAdd(&cur[d >> 7], 1);
            __builtin_nontemporal_store((s << 7) | (d & 127), &st[p]);
        }
    }
}

// P4: per-bucket fine CSR: LDS hist+scan -> rowptr slice; LDS scatter -> ssrc
__global__ __launch_bounds__(256)
void p4_fine(const int* __restrict__ baseG, const int* __restrict__ stage,
             int* __restrict__ rowptr, int* __restrict__ ssrc)
{
    __shared__ int out[8192];
    __shared__ int hist[128], off[128], curs[128];
    const int y = blockIdx.y, u = blockIdx.x;
    const int t = threadIdx.x;
    const int base = baseG[y * (NBU + 1) + u];
    const int cnt_ = baseG[y * (NBU + 1) + u + 1] - base;
    const int n0 = u * 128;
    if (t < 128) hist[t] = 0;
    __syncthreads();
    const int* st = stage + (size_t)y * EE + base;
    for (int i = t; i < cnt_; i += 256) atomicAdd(&hist[st[i] & 127], 1);
    __syncthreads();
    if (t < 64) {
        const int v0 = hist[t];
        const int i0 = wave_incl_scan(v0, t);
        off[t] = i0 - v0;
        const int tot0 = __shfl(i0, 63, 64);
        const int v1 = hist[64 + t];
        const int i1 = wave_incl_scan(v1, t);
        off[64 + t] = tot0 + i1 - v1;
    }
    __syncthreads();
    if (t < 128) {
        curs[t] = off[t];
        const int node = n0 + t;
        if (node < NN) rowptr[y * (NN + 1) + node] = base + off[t];
    }
    if (t == 0 && u == 0) rowptr[y * (NN + 1) + NN] = EE;
    __syncthreads();
    for (int i = t; i < cnt_; i += 256) {
        const int w = st[i];
        const int p = atomicAdd(&curs[w & 127], 1);
        if (p < 8192) out[p] = w >> 7;      // clamp: statistically unreachable
    }
    __syncthreads();
    int* dp = ssrc + (size_t)y * EE + base;
    const int lim = (cnt_ < 8192) ? cnt_ : 8192;
    for (int i = t; i < lim; i += 256)
        __builtin_nontemporal_store(out[i], &dp[i]);
}

// ---------------------------------------------------------------------------
// bf16 gather-mean: one block (128 thr) per dst node.
// 32 lanes x 16B cover one 512B source row; 4 edge slots in flight.
// ---------------------------------------------------------------------------
__global__ __launch_bounds__(128)
void agg_bf(const unsigned short* __restrict__ feat, const int* __restrict__ rowptr,
            const int* __restrict__ ssrc, unsigned short* __restrict__ out)
{
    __shared__ float red[32][8];
    const int node = blockIdx.x;
    const int t = threadIdx.x;
    const int slot = t >> 5;        // 0..3 edge slot
    const int c = t & 31;           // 16B chunk -> channels 8c..8c+7
    const int beg = rowptr[node], end = rowptr[node + 1];
    const int deg = end - beg;

    float a0=0.f,a1=0.f,a2=0.f,a3=0.f,a4=0.f,a5=0.f,a6=0.f,a7=0.f;
    for (int i = beg + slot; i < end; i += 4) {
        const uint4 v = *(const uint4*)(feat + ((size_t)ssrc[i] << 8) + c * 8);
        a0 += bflo(v.x); a1 += bfhi(v.x);
        a2 += bflo(v.y); a3 += bfhi(v.y);
        a4 += bflo(v.z); a5 += bfhi(v.z);
        a6 += bflo(v.w); a7 += bfhi(v.w);
    }
    // slot pairs within each wave: lane l <-> l^32
    a0 += __shfl_xor(a0, 32, 64); a1 += __shfl_xor(a1, 32, 64);
    a2 += __shfl_xor(a2, 32, 64); a3 += __shfl_xor(a3, 32, 64);
    a4 += __shfl_xor(a4, 32, 64); a5 += __shfl_xor(a5, 32, 64);
    a6 += __shfl_xor(a6, 32, 64); a7 += __shfl_xor(a7, 32, 64);
    // cross-wave: wave1 lanes 0..31 (slots 2+3) -> LDS
    if (t >= 64 && t < 96) {
        red[c][0]=a0; red[c][1]=a1; red[c][2]=a2; red[c][3]=a3;
        red[c][4]=a4; red[c][5]=a5; red[c][6]=a6; red[c][7]=a7;
    }
    __syncthreads();
    if (t < 32) {
        a0 += red[c][0]; a1 += red[c][1]; a2 += red[c][2]; a3 += red[c][3];
        a4 += red[c][4]; a5 += red[c][5]; a6 += red[c][6]; a7 += red[c][7];
        const float inv = 1.0f / fmaxf((float)deg, 1.0f);
        uint4 o;
        o.x = (unsigned int)f2bf(a0 * inv) | ((unsigned int)f2bf(a1 * inv) << 16);
        o.y = (unsigned int)f2bf(a2 * inv) | ((unsigned int)f2bf(a3 * inv) << 16);
        o.z = (unsigned int)f2bf(a4 * inv) | ((unsigned int)f2bf(a5 * inv) << 16);
        o.w = (unsigned int)f2bf(a6 * inv) | ((unsigned int)f2bf(a7 * inv) << 16);
        *(uint4*)(out + ((size_t)node << 8) + c * 8) = o;
    }
}

// ---------------------------------------------------------------------------
// converts
// ---------------------------------------------------------------------------
__global__ __launch_bounds__(256)
void f2bf4_kernel(const float* __restrict__ in, unsigned short* __restrict__ out, int n4)
{
    const int i = blockIdx.x * 256 + threadIdx.x;
    if (i < n4) {
        const float4 v = ((const float4*)in)[i];
        ushort4 o;
        o.x = f2bf(v.x); o.y = f2bf(v.y); o.z = f2bf(v.z); o.w = f2bf(v.w);
        ((ushort4*)out)[i] = o;
    }
}

// W [K][256] fp32 -> WT [256][KT] bf16 at column offset koff
__global__ __launch_bounds__(256)
void wt_kernel(const float* __restrict__ W, unsigned short* __restrict__ WT,
               int K, int KT, int koff)
{
    const int idx = blockIdx.x * 256 + threadIdx.x;
    if (idx < K * 256) {
        const int k = idx >> 8, n = idx & 255;
        WT[(size_t)n * KT + koff + k] = f2bf(W[(size_t)k * 256 + n]);
    }
}

// ---------------------------------------------------------------------------
extern "C" void kernel_launch(void* const* d_in, const int* in_sizes, int n_in,
                              void* d_out, int out_size, void* d_ws, size_t ws_size,
                              hipStream_t stream)
{
    const float* x_A    = (const float*)d_in[0];
    const float* x_B    = (const float*)d_in[1];
    const int*   e_ab   = (const int*)d_in[4];
    const int*   e_ba   = (const int*)d_in[5];
    const float* lin_A  = (const float*)d_in[6];
    const float* lin_B  = (const float*)d_in[7];
    const float* bias_A = (const float*)d_in[8];
    const float* bias_B = (const float*)d_in[9];
    const float* Wl_ab0 = (const float*)d_in[10]; const float* bl_ab0 = (const float*)d_in[11]; const float* Wr_ab0 = (const float*)d_in[12];
    const float* Wl_ba0 = (const float*)d_in[13]; const float* bl_ba0 = (const float*)d_in[14]; const float* Wr_ba0 = (const float*)d_in[15];
    const float* Wl_ab1 = (const float*)d_in[16]; const float* bl_ab1 = (const float*)d_in[17]; const float* Wr_ab1 = (const float*)d_in[18];
    const float* Wl_ba1 = (const float*)d_in[19]; const float* bl_ba1 = (const float*)d_in[20]; const float* Wr_ba1 = (const float*)d_in[21];

    float* gA = (float*)d_out;
    float* gB = gA + (size_t)NN * 256;

    // ---- workspace carve (ushort units) ----
    const size_t HALF = (size_t)NN * 128;           // 12.8M
    const size_t FULL = (size_t)NN * 256;           // 25.6M
    unsigned short* xb    = (unsigned short*)d_ws;  // xbA|xbB; later l0A
    unsigned short* xbA   = xb;
    unsigned short* xbB   = xb + HALF;
    unsigned short* l0A   = xb;                     // reuse after proj GEMMs
    unsigned short* projA = xb + FULL;              // later l0B
    unsigned short* l0B   = projA;
    unsigned short* projB = projA + FULL;
    unsigned short* aggb  = projB + FULL;
    unsigned short* linAT = aggb + FULL;            // [256][128]
    unsigned short* linBT = linAT + 256 * 128;
    unsigned short* WTba0 = linBT + 256 * 128;      // [256][512] each
    unsigned short* WTab0 = WTba0 + 256 * 512;
    unsigned short* WTba1 = WTab0 + 256 * 512;
    unsigned short* WTab1 = WTba1 + 256 * 512;
    int* ssrc2   = (int*)(WTab1 + 256 * 512);       // [2][EE]  (0=ba, 1=ab)
    int* rowptr2 = ssrc2 + 2 * (size_t)EE;          // [2][NN+1]

    // CSR-build scratch aliased onto aggb (dead until first agg_bf)
    int* stage    = (int*)aggb;                     // [2][EE] packed (s<<7)|dfine
    int* cnt      = stage + 2 * (size_t)EE;         // [2][NCH][NBU]
    int* blockOff = cnt + 2 * NCH * NBU;            // [2][NCH][NBU]
    int* baseG    = blockOff + 2 * NCH * NBU;       // [2][NBU+1]

    int* ssrc_ba   = ssrc2;
    int* ssrc_ab   = ssrc2 + EE;
    int* rowptr_ba = rowptr2;
    int* rowptr_ab = rowptr2 + (NN + 1);

    const int* src_ab = e_ab;  const int* dst_ab = e_ab + EE;
    const int* src_ba = e_ba;  const int* dst_ba = e_ba + EE;

    const dim3 gg((NN + 127) / 128, 2);             // 782 x 2
    const dim3 gCh(NCH, 2);
    const dim3 gBu(NBU, 2);

    // ---- CSR build (bucketed, no global atomics, coalesced) ----
    p1_count<<<gCh, 256, 0, stream>>>(dst_ba, dst_ab, cnt);
    p2_scan<<<1, 1024, 0, stream>>>(cnt, baseG);
    p2b_off<<<(2 * NBU + 255) / 256, 256, 0, stream>>>(cnt, baseG, blockOff);
    p3_scatter<<<gCh, 256, 0, stream>>>(src_ba, dst_ba, src_ab, dst_ab, blockOff, stage);
    p4_fine<<<gBu, 256, 0, stream>>>(baseG, stage, rowptr2, ssrc2);

    // ---- convert inputs & weights to bf16 (weights transposed) ----
    f2bf4_kernel<<<(int)(HALF / 4 + 255) / 256, 256, 0, stream>>>(x_A, xbA, (int)(HALF / 4));
    f2bf4_kernel<<<(int)(HALF / 4 + 255) / 256, 256, 0, stream>>>(x_B, xbB, (int)(HALF / 4));
    wt_kernel<<<128, 256, 0, stream>>>(lin_A, linAT, 128, 128, 0);
    wt_kernel<<<128, 256, 0, stream>>>(lin_B, linBT, 128, 128, 0);
    wt_kernel<<<256, 256, 0, stream>>>(Wl_ba0, WTba0, 256, 512, 0);
    wt_kernel<<<256, 256, 0, stream>>>(Wr_ba0, WTba0, 256, 512, 256);
    wt_kernel<<<256, 256, 0, stream>>>(Wl_ab0, WTab0, 256, 512, 0);
    wt_kernel<<<256, 256, 0, stream>>>(Wr_ab0, WTab0, 256, 512, 256);
    wt_kernel<<<256, 256, 0, stream>>>(Wl_ba1, WTba1, 256, 512, 0);
    wt_kernel<<<256, 256, 0, stream>>>(Wr_ba1, WTba1, 256, 512, 256);
    wt_kernel<<<256, 256, 0, stream>>>(Wl_ab1, WTab1, 256, 512, 0);
    wt_kernel<<<256, 256, 0, stream>>>(Wr_ab1, WTab1, 256, 512, 256);

    // ---- input projections (bf16 out) ----
    gemm_mfma<0, 128, 0><<<gg, 256, 0, stream>>>(nullptr, xbA, linAT, nullptr, nullptr, projA, NN);
    gemm_mfma<0, 128, 0><<<gg, 256, 0, stream>>>(nullptr, xbB, linBT, nullptr, nullptr, projB, NN);

    // ---- layer 0 ----
    agg_bf<<<NN, 128, 0, stream>>>(projB, rowptr_ba, ssrc_ba, aggb);          // mean B->A
    gemm_mfma<256, 256, 0><<<gg, 256, 0, stream>>>(aggb, projA, WTba0, bl_ba0, nullptr, l0A, NN);
    agg_bf<<<NN, 128, 0, stream>>>(projA, rowptr_ab, ssrc_ab, aggb);          // mean A->B
    gemm_mfma<256, 256, 0><<<gg, 256, 0, stream>>>(aggb, projB, WTab0, bl_ab0, nullptr, l0B, NN);

    // ---- layer 1 (final: fp32 + per-type bias + sigmoid into d_out) ----
    agg_bf<<<NN, 128, 0, stream>>>(l0B, rowptr_ba, ssrc_ba, aggb);            // mean B->A
    gemm_mfma<256, 256, 1><<<gg, 256, 0, stream>>>(aggb, l0A, WTba1, bl_ba1, bias_A, gA, NN);
    agg_bf<<<NN, 128, 0, stream>>>(l0A, rowptr_ab, ssrc_ab, aggb);            // mean A->B
    gemm_mfma<256, 256, 1><<<gg, 256, 0, stream>>>(aggb, l0B, WTab1, bl_ab1, bias_B, gB, NN);
}

// Round 4
// 1257.187 us; speedup vs baseline: 1.2723x; 1.0340x over previous
//
#include <hip/hip_runtime.h>
#include <math.h>

#define NN 100000
#define EE 1600000
#define NBU 782          // coarse buckets = ceil(NN/128)
#define NCH 196          // edge chunks  = ceil(EE/8192)
#define CHUNK 8192
#define MB64 1563        // ceil(NN/64) row-blocks for fused kernel

typedef short s16x8 __attribute__((ext_vector_type(8)));
typedef float f32x4 __attribute__((ext_vector_type(4)));

union FragU { uint4 u; s16x8 s; };

__device__ __forceinline__ unsigned short f2bf(float x) {
    unsigned int u = __float_as_uint(x);
    u = (u + 0x7fff + ((u >> 16) & 1)) >> 16;   // round-to-nearest-even
    return (unsigned short)u;
}
__device__ __forceinline__ float bf2f(unsigned short b) {
    return __uint_as_float(((unsigned int)b) << 16);
}
__device__ __forceinline__ float bflo(unsigned int u) { return __uint_as_float(u << 16); }
__device__ __forceinline__ float bfhi(unsigned int u) { return __uint_as_float(u & 0xffff0000u); }

__device__ __forceinline__ void gload16(const unsigned short* g, unsigned short* l) {
    __builtin_amdgcn_global_load_lds(
        (const __attribute__((address_space(1))) unsigned int*)g,
        (__attribute__((address_space(3))) unsigned int*)l, 16, 0, 0);
}

// ---------------------------------------------------------------------------
// bf16 MFMA GEMM (m97 structure) — used only for the input projections now.
// BM=BN=128, BK=32, 256 thr = 4 waves (2x2). A row-major bf16 stride K2,
// BT = B transposed [256][K2]. MODE 0: bf16 out.
// ---------------------------------------------------------------------------
template<int K1, int K2, int MODE>
__global__ __launch_bounds__(256)
void gemm_mfma(const unsigned short* __restrict__ A1,
               const unsigned short* __restrict__ A2,
               const unsigned short* __restrict__ BT,
               const float* __restrict__ bl, const float* __restrict__ b2,
               void* __restrict__ Cout, int M)
{
    constexpr int KT = K1 + K2;
    __shared__ __align__(16) unsigned short As[128 * 32];
    __shared__ __align__(16) unsigned short Bs[128 * 32];

    const int tid  = threadIdx.x;
    const int w    = tid >> 6, lane = tid & 63;
    const int l15  = lane & 15, g = lane >> 4;
    const int m0   = blockIdx.x * 128;
    const int n0   = blockIdx.y * 128;
    const int wm   = (w >> 1) * 64, wn = (w & 1) * 64;

    f32x4 acc[4][4];
#pragma unroll
    for (int i = 0; i < 4; i++)
#pragma unroll
        for (int j = 0; j < 4; j++) { acc[i][j][0]=0.f; acc[i][j][1]=0.f; acc[i][j][2]=0.f; acc[i][j][3]=0.f; }

    for (int k0 = 0; k0 < KT; k0 += 32) {
        const unsigned short* Ap; int astr, kloc;
        if (K1 > 0 && k0 < K1) { Ap = A1; astr = K1; kloc = k0; }
        else                   { Ap = A2; astr = K2; kloc = k0 - K1; }

#pragma unroll
        for (int c = 0; c < 2; c++) {
            const int chunk = ((w * 2 + c) << 6) + lane;   // 16B chunk id in tile
            const int row = chunk >> 2, kc = chunk & 3;
            int rg = m0 + row; if (rg > M - 1) rg = M - 1;
            gload16(Ap + (size_t)rg * astr + kloc + kc * 8, As + (w * 2 + c) * 512);
            gload16(BT + (size_t)(n0 + row) * KT + k0 + kc * 8, Bs + (w * 2 + c) * 512);
        }
        __syncthreads();

        FragU a[4], b[4];
#pragma unroll
        for (int i = 0; i < 4; i++) {
            a[i].u = *(const uint4*)(As + (wm + i * 16 + l15) * 32 + g * 8);
            b[i].u = *(const uint4*)(Bs + (wn + i * 16 + l15) * 32 + g * 8);
        }
#pragma unroll
        for (int i = 0; i < 4; i++)
#pragma unroll
            for (int j = 0; j < 4; j++)
                acc[i][j] = __builtin_amdgcn_mfma_f32_16x16x32_bf16(a[i].s, b[j].s, acc[i][j], 0, 0, 0);
        __syncthreads();
    }

    float badd[4];
#pragma unroll
    for (int j = 0; j < 4; j++) {
        const int col = n0 + wn + j * 16 + l15;
        badd[j] = bl ? bl[col] : 0.0f;
        if (MODE == 1) badd[j] += b2[col];
    }
#pragma unroll
    for (int i = 0; i < 4; i++) {
#pragma unroll
        for (int r = 0; r < 4; r++) {
            const int rowg = m0 + wm + i * 16 + g * 4 + r;
            if (rowg < M) {
#pragma unroll
                for (int j = 0; j < 4; j++) {
                    const int col = n0 + wn + j * 16 + l15;
                    float t = acc[i][j][r] + badd[j];
                    if (MODE == 1) {
                        t = 1.0f / (1.0f + __expf(-t));
                        ((float*)Cout)[(size_t)rowg * 256 + col] = t;
                    } else {
                        ((unsigned short*)Cout)[(size_t)rowg * 256 + col] = f2bf(t);
                    }
                }
            }
        }
    }
}

// ---------------------------------------------------------------------------
// Fused SAGE conv: gather-mean into LDS A-tile, then GEMM vs BT=[Wl^T|Wr^T].
// Block: 64 dst rows x 256 out cols, 256 thr = 4 waves (1M x 4N).
// blockIdx.y selects edge-type/dst-type (0: ->A, 1: ->B).
// LDS: Abuf 32K (XOR-swizzled) + Bs 16K + As2 4K = 52 KB -> 3 blocks/CU.
// MODE 0: bf16 out (+bl). MODE 1: fp32 sigmoid(acc+bl+b2) out.
// ---------------------------------------------------------------------------
template<int MODE>
__global__ __launch_bounds__(256)
void fused_sage(const int* __restrict__ rowptr2, const int* __restrict__ ssrc2,
                const unsigned short* __restrict__ fsrc0, const unsigned short* __restrict__ fsrc1,
                const unsigned short* __restrict__ fdst0, const unsigned short* __restrict__ fdst1,
                const unsigned short* __restrict__ BT0, const unsigned short* __restrict__ BT1,
                const float* __restrict__ bl0, const float* __restrict__ bl1,
                const float* __restrict__ b20, const float* __restrict__ b21,
                void* __restrict__ out0, void* __restrict__ out1)
{
    __shared__ __align__(16) unsigned short Abuf[64 * 256];   // swizzled mean tile
    __shared__ __align__(16) unsigned short Bs[256 * 32];
    __shared__ __align__(16) unsigned short As2[64 * 32];

    const int y   = blockIdx.y;
    const int m0  = blockIdx.x * 64;
    const int tid = threadIdx.x;

    const int* rowptr = rowptr2 + y * (NN + 1);
    const int* ssrc   = ssrc2 + (size_t)y * EE;
    const unsigned short* fsrc = y ? fsrc1 : fsrc0;
    const unsigned short* fdst = y ? fdst1 : fdst0;
    const unsigned short* BT   = y ? BT1 : BT0;
    const float* bl = y ? bl1 : bl0;
    const float* b2 = y ? b21 : b20;
    void* out       = y ? out1 : out0;

    // ---- phase 1: gather-mean. 8 groups x 32 lanes; each group 8 rows. ----
    {
        const int grp = tid >> 5, c = tid & 31;   // c: 16B chunk -> ch 8c..8c+7
        for (int q = 0; q < 8; q++) {
            const int r = grp * 8 + q;
            const int node = m0 + r;
            uint4 o = make_uint4(0u, 0u, 0u, 0u);
            if (node < NN) {
                const int beg = rowptr[node], end = rowptr[node + 1];
                float a0=0.f,a1=0.f,a2=0.f,a3=0.f,a4=0.f,a5=0.f,a6=0.f,a7=0.f;
                int i = beg;
                for (; i + 4 <= end; i += 4) {
                    const int s0 = ssrc[i], s1 = ssrc[i+1], s2 = ssrc[i+2], s3 = ssrc[i+3];
                    const uint4 v0 = *(const uint4*)(fsrc + ((size_t)s0 << 8) + c * 8);
                    const uint4 v1 = *(const uint4*)(fsrc + ((size_t)s1 << 8) + c * 8);
                    const uint4 v2 = *(const uint4*)(fsrc + ((size_t)s2 << 8) + c * 8);
                    const uint4 v3 = *(const uint4*)(fsrc + ((size_t)s3 << 8) + c * 8);
                    a0 += bflo(v0.x)+bflo(v1.x)+bflo(v2.x)+bflo(v3.x);
                    a1 += bfhi(v0.x)+bfhi(v1.x)+bfhi(v2.x)+bfhi(v3.x);
                    a2 += bflo(v0.y)+bflo(v1.y)+bflo(v2.y)+bflo(v3.y);
                    a3 += bfhi(v0.y)+bfhi(v1.y)+bfhi(v2.y)+bfhi(v3.y);
                    a4 += bflo(v0.z)+bflo(v1.z)+bflo(v2.z)+bflo(v3.z);
                    a5 += bfhi(v0.z)+bfhi(v1.z)+bfhi(v2.z)+bfhi(v3.z);
                    a6 += bflo(v0.w)+bflo(v1.w)+bflo(v2.w)+bflo(v3.w);
                    a7 += bfhi(v0.w)+bfhi(v1.w)+bfhi(v2.w)+bfhi(v3.w);
                }
                for (; i < end; ++i) {
                    const uint4 v = *(const uint4*)(fsrc + ((size_t)ssrc[i] << 8) + c * 8);
                    a0 += bflo(v.x); a1 += bfhi(v.x);
                    a2 += bflo(v.y); a3 += bfhi(v.y);
                    a4 += bflo(v.z); a5 += bfhi(v.z);
                    a6 += bflo(v.w); a7 += bfhi(v.w);
                }
                const float inv = 1.0f / fmaxf((float)(end - beg), 1.0f);
                o.x = (unsigned int)f2bf(a0*inv) | ((unsigned int)f2bf(a1*inv) << 16);
                o.y = (unsigned int)f2bf(a2*inv) | ((unsigned int)f2bf(a3*inv) << 16);
                o.z = (unsigned int)f2bf(a4*inv) | ((unsigned int)f2bf(a5*inv) << 16);
                o.w = (unsigned int)f2bf(a6*inv) | ((unsigned int)f2bf(a7*inv) << 16);
            }
            // XOR-swizzle: 16B chunk index ^ (row&7); conflict-free frag reads
            const int idx = r * 256 + ((c * 8) ^ ((r & 7) << 3));
            *(uint4*)(Abuf + idx) = o;
        }
    }
    // (no barrier here: iteration-0 barrier below covers Abuf visibility)

    const int w = tid >> 6, lane = tid & 63;
    const int l15 = lane & 15, g = lane >> 4;
    const int wn = w * 64;

    f32x4 acc[4][4];
#pragma unroll
    for (int i = 0; i < 4; i++)
#pragma unroll
        for (int j = 0; j < 4; j++) { acc[i][j][0]=0.f; acc[i][j][1]=0.f; acc[i][j][2]=0.f; acc[i][j][3]=0.f; }

    for (int k0 = 0; k0 < 512; k0 += 32) {
        // stage B tile [256 rows][32 k]: 4 gload16 per thread
#pragma unroll
        for (int cc = 0; cc < 4; cc++) {
            const int chunk = cc * 256 + w * 64 + lane;
            const int row = chunk >> 2, kc = chunk & 3;
            gload16(BT + (size_t)row * 512 + k0 + kc * 8, Bs + (cc * 256 + w * 64) * 8);
        }
        if (k0 >= 256) {   // stage root-feature tile [64][32]
            const int chunk = w * 64 + lane;
            const int row = chunk >> 2, kc = chunk & 3;
            int rg = m0 + row; if (rg > NN - 1) rg = NN - 1;
            gload16(fdst + ((size_t)rg << 8) + (k0 - 256) + kc * 8, As2 + w * 512);
        }
        __syncthreads();

        FragU a[4], b[4];
        if (k0 < 256) {
#pragma unroll
            for (int i = 0; i < 4; i++) {
                const int row = i * 16 + l15;
                a[i].u = *(const uint4*)(Abuf + row * 256 + ((k0 + g * 8) ^ ((row & 7) << 3)));
            }
        } else {
#pragma unroll
            for (int i = 0; i < 4; i++)
                a[i].u = *(const uint4*)(As2 + (i * 16 + l15) * 32 + g * 8);
        }
#pragma unroll
        for (int j = 0; j < 4; j++)
            b[j].u = *(const uint4*)(Bs + (wn + j * 16 + l15) * 32 + g * 8);
#pragma unroll
        for (int i = 0; i < 4; i++)
#pragma unroll
            for (int j = 0; j < 4; j++)
                acc[i][j] = __builtin_amdgcn_mfma_f32_16x16x32_bf16(a[i].s, b[j].s, acc[i][j], 0, 0, 0);
        __syncthreads();
    }

    // epilogue: C/D layout col=lane&15, row=(lane>>4)*4+reg
    float badd[4];
#pragma unroll
    for (int j = 0; j < 4; j++) {
        const int col = wn + j * 16 + l15;
        badd[j] = bl[col];
        if (MODE == 1) badd[j] += b2[col];
    }
#pragma unroll
    for (int i = 0; i < 4; i++) {
#pragma unroll
        for (int r = 0; r < 4; r++) {
            const int rowg = m0 + i * 16 + g * 4 + r;
            if (rowg < NN) {
#pragma unroll
                for (int j = 0; j < 4; j++) {
                    const int col = wn + j * 16 + l15;
                    float t = acc[i][j][r] + badd[j];
                    if (MODE == 1) {
                        t = 1.0f / (1.0f + __expf(-t));
                        ((float*)out)[(size_t)rowg * 256 + col] = t;
                    } else {
                        ((unsigned short*)out)[(size_t)rowg * 256 + col] = f2bf(t);
                    }
                }
            }
        }
    }
}

__device__ __forceinline__ int wave_incl_scan(int v, int lane)
{
#pragma unroll
    for (int off = 1; off < 64; off <<= 1) {
        int t = __shfl_up(v, off, 64);
        if (lane >= off) v += t;
    }
    return v;
}

// ---------------------------------------------------------------------------
// Bucketed CSR build: all random access in LDS; global traffic coalesced.
// Coarse bucket = dst>>7 (128 nodes). Stage word = (src<<7)|(dst&127).
// ---------------------------------------------------------------------------
__global__ __launch_bounds__(256)
void p1_count(const int* __restrict__ dba, const int* __restrict__ dab,
              int* __restrict__ cnt)
{
    __shared__ int h[NBU];
    const int y = blockIdx.y, b = blockIdx.x;
    for (int i = threadIdx.x; i < NBU; i += 256) h[i] = 0;
    __syncthreads();
    const int* D = y ? dab : dba;
    const int base = b * CHUNK;
    for (int i = threadIdx.x; i < CHUNK; i += 256) {
        const int e = base + i;
        if (e < EE) atomicAdd(&h[D[e] >> 7], 1);
    }
    __syncthreads();
    for (int i = threadIdx.x; i < NBU; i += 256)
        cnt[(y * NCH + b) * NBU + i] = h[i];
}

__global__ __launch_bounds__(1024)
void p2_scan(const int* __restrict__ cnt, int* __restrict__ baseG)
{
    __shared__ int tot[2 * NBU];
    const int tid = threadIdx.x;
    for (int i = tid; i < 2 * NBU; i += 1024) {
        const int y = i / NBU, u = i - y * NBU;
        int s = 0;
#pragma unroll 4
        for (int b = 0; b < NCH; b++) s += cnt[(y * NCH + b) * NBU + u];
        tot[i] = s;
    }
    __syncthreads();
    const int lane = tid & 63, wid = tid >> 6;
    if (wid < 2) {
        int run = 0;
        for (int c = 0; c < NBU; c += 64) {
            const int ui = c + lane;
            const int v = (ui < NBU) ? tot[wid * NBU + ui] : 0;
            const int incl = wave_incl_scan(v, lane);
            if (ui < NBU) baseG[wid * (NBU + 1) + ui] = run + incl - v;
            run += __shfl(incl, 63, 64);
        }
        if (lane == 0) baseG[wid * (NBU + 1) + NBU] = run;   // == EE
    }
}

__global__ __launch_bounds__(256)
void p2b_off(const int* __restrict__ cnt, const int* __restrict__ baseG,
             int* __restrict__ blockOff)
{
    const int i = blockIdx.x * 256 + threadIdx.x;
    if (i >= 2 * NBU) return;
    const int y = i / NBU, u = i - y * NBU;
    int run = baseG[y * (NBU + 1) + u];
#pragma unroll 4
    for (int b = 0; b < NCH; b++) {
        blockOff[(y * NCH + b) * NBU + u] = run;
        run += cnt[(y * NCH + b) * NBU + u];
    }
}

__global__ __launch_bounds__(256)
void p3_scatter(const int* __restrict__ sba, const int* __restrict__ dba,
                const int* __restrict__ sab, const int* __restrict__ dab,
                const int* __restrict__ blockOff, int* __restrict__ stage)
{
    __shared__ int cur[NBU];
    const int y = blockIdx.y, b = blockIdx.x;
    for (int i = threadIdx.x; i < NBU; i += 256)
        cur[i] = blockOff[(y * NCH + b) * NBU + i];
    __syncthreads();
    const int* S = y ? sab : sba;
    const int* D = y ? dab : dba;
    int* st = stage + (size_t)y * EE;
    const int base = b * CHUNK;
    for (int i = threadIdx.x; i < CHUNK; i += 256) {
        const int e = base + i;
        if (e < EE) {
            const int d = D[e], s = S[e];
            const int p = atomicAdd(&cur[d >> 7], 1);
            __builtin_nontemporal_store((s << 7) | (d & 127), &st[p]);
        }
    }
}

__global__ __launch_bounds__(256)
void p4_fine(const int* __restrict__ baseG, const int* __restrict__ stage,
             int* __restrict__ rowptr, int* __restrict__ ssrc)
{
    __shared__ int out[8192];
    __shared__ int hist[128], off[128], curs[128];
    const int y = blockIdx.y, u = blockIdx.x;
    const int t = threadIdx.x;
    const int base = baseG[y * (NBU + 1) + u];
    const int cnt_ = baseG[y * (NBU + 1) + u + 1] - base;
    const int n0 = u * 128;
    if (t < 128) hist[t] = 0;
    __syncthreads();
    const int* st = stage + (size_t)y * EE + base;
    for (int i = t; i < cnt_; i += 256) atomicAdd(&hist[st[i] & 127], 1);
    __syncthreads();
    if (t < 64) {
        const int v0 = hist[t];
        const int i0 = wave_incl_scan(v0, t);
        off[t] = i0 - v0;
        const int tot0 = __shfl(i0, 63, 64);
        const int v1 = hist[64 + t];
        const int i1 = wave_incl_scan(v1, t);
        off[64 + t] = tot0 + i1 - v1;
    }
    __syncthreads();
    if (t < 128) {
        curs[t] = off[t];
        const int node = n0 + t;
        if (node < NN) rowptr[y * (NN + 1) + node] = base + off[t];
    }
    if (t == 0 && u == 0) rowptr[y * (NN + 1) + NN] = EE;
    __syncthreads();
    for (int i = t; i < cnt_; i += 256) {
        const int w = st[i];
        const int p = atomicAdd(&curs[w & 127], 1);
        if (p < 8192) out[p] = w >> 7;      // clamp: statistically unreachable
    }
    __syncthreads();
    int* dp = ssrc + (size_t)y * EE + base;
    const int lim = (cnt_ < 8192) ? cnt_ : 8192;
    for (int i = t; i < lim; i += 256)
        __builtin_nontemporal_store(out[i], &dp[i]);
}

// ---------------------------------------------------------------------------
// converts
// ---------------------------------------------------------------------------
__global__ __launch_bounds__(256)
void f2bf4_kernel(const float* __restrict__ in, unsigned short* __restrict__ out, int n4)
{
    const int i = blockIdx.x * 256 + threadIdx.x;
    if (i < n4) {
        const float4 v = ((const float4*)in)[i];
        ushort4 o;
        o.x = f2bf(v.x); o.y = f2bf(v.y); o.z = f2bf(v.z); o.w = f2bf(v.w);
        ((ushort4*)out)[i] = o;
    }
}

// W [K][256] fp32 -> WT [256][KT] bf16 at column offset koff
__global__ __launch_bounds__(256)
void wt_kernel(const float* __restrict__ W, unsigned short* __restrict__ WT,
               int K, int KT, int koff)
{
    const int idx = blockIdx.x * 256 + threadIdx.x;
    if (idx < K * 256) {
        const int k = idx >> 8, n = idx & 255;
        WT[(size_t)n * KT + koff + k] = f2bf(W[(size_t)k * 256 + n]);
    }
}

// ---------------------------------------------------------------------------
extern "C" void kernel_launch(void* const* d_in, const int* in_sizes, int n_in,
                              void* d_out, int out_size, void* d_ws, size_t ws_size,
                              hipStream_t stream)
{
    const float* x_A    = (const float*)d_in[0];
    const float* x_B    = (const float*)d_in[1];
    const int*   e_ab   = (const int*)d_in[4];
    const int*   e_ba   = (const int*)d_in[5];
    const float* lin_A  = (const float*)d_in[6];
    const float* lin_B  = (const float*)d_in[7];
    const float* bias_A = (const float*)d_in[8];
    const float* bias_B = (const float*)d_in[9];
    const float* Wl_ab0 = (const float*)d_in[10]; const float* bl_ab0 = (const float*)d_in[11]; const float* Wr_ab0 = (const float*)d_in[12];
    const float* Wl_ba0 = (const float*)d_in[13]; const float* bl_ba0 = (const float*)d_in[14]; const float* Wr_ba0 = (const float*)d_in[15];
    const float* Wl_ab1 = (const float*)d_in[16]; const float* bl_ab1 = (const float*)d_in[17]; const float* Wr_ab1 = (const float*)d_in[18];
    const float* Wl_ba1 = (const float*)d_in[19]; const float* bl_ba1 = (const float*)d_in[20]; const float* Wr_ba1 = (const float*)d_in[21];

    float* gA = (float*)d_out;
    float* gB = gA + (size_t)NN * 256;

    // ---- workspace carve (ushort units) ----
    const size_t HALF = (size_t)NN * 128;           // 12.8M
    const size_t FULL = (size_t)NN * 256;           // 25.6M
    unsigned short* xb    = (unsigned short*)d_ws;  // xbA|xbB; later l0A
    unsigned short* xbA   = xb;
    unsigned short* xbB   = xb + HALF;
    unsigned short* l0A   = xb;                     // reuse after proj GEMMs
    unsigned short* projA = xb + FULL;
    unsigned short* projB = projA + FULL;
    unsigned short* aggb  = projB + FULL;           // CSR scratch, then l0B
    unsigned short* l0B   = aggb;                   // (stage dead before layer 0)
    unsigned short* linAT = aggb + FULL;            // [256][128]
    unsigned short* linBT = linAT + 256 * 128;
    unsigned short* WTba0 = linBT + 256 * 128;      // [256][512] each
    unsigned short* WTab0 = WTba0 + 256 * 512;
    unsigned short* WTba1 = WTab0 + 256 * 512;
    unsigned short* WTab1 = WTba1 + 256 * 512;
    int* ssrc2   = (int*)(WTab1 + 256 * 512);       // [2][EE]  (0=ba, 1=ab)
    int* rowptr2 = ssrc2 + 2 * (size_t)EE;          // [2][NN+1]

    // CSR-build scratch aliased onto aggb (dead before layer 0 writes l0B)
    int* stage    = (int*)aggb;                     // [2][EE] packed (s<<7)|dfine
    int* cnt      = stage + 2 * (size_t)EE;         // [2][NCH][NBU]
    int* blockOff = cnt + 2 * NCH * NBU;            // [2][NCH][NBU]
    int* baseG    = blockOff + 2 * NCH * NBU;       // [2][NBU+1]

    const int* src_ab = e_ab;  const int* dst_ab = e_ab + EE;
    const int* src_ba = e_ba;  const int* dst_ba = e_ba + EE;

    const dim3 gg((NN + 127) / 128, 2);             // proj GEMM grid 782 x 2
    const dim3 gCh(NCH, 2);
    const dim3 gBu(NBU, 2);
    const dim3 gF(MB64, 2);                         // fused grid 1563 x 2

    // ---- CSR build (bucketed, no global atomics, coalesced) ----
    p1_count<<<gCh, 256, 0, stream>>>(dst_ba, dst_ab, cnt);
    p2_scan<<<1, 1024, 0, stream>>>(cnt, baseG);
    p2b_off<<<(2 * NBU + 255) / 256, 256, 0, stream>>>(cnt, baseG, blockOff);
    p3_scatter<<<gCh, 256, 0, stream>>>(src_ba, dst_ba, src_ab, dst_ab, blockOff, stage);
    p4_fine<<<gBu, 256, 0, stream>>>(baseG, stage, rowptr2, ssrc2);

    // ---- convert inputs & weights to bf16 (weights transposed) ----
    f2bf4_kernel<<<(int)(HALF / 4 + 255) / 256, 256, 0, stream>>>(x_A, xbA, (int)(HALF / 4));
    f2bf4_kernel<<<(int)(HALF / 4 + 255) / 256, 256, 0, stream>>>(x_B, xbB, (int)(HALF / 4));
    wt_kernel<<<128, 256, 0, stream>>>(lin_A, linAT, 128, 128, 0);
    wt_kernel<<<128, 256, 0, stream>>>(lin_B, linBT, 128, 128, 0);
    wt_kernel<<<256, 256, 0, stream>>>(Wl_ba0, WTba0, 256, 512, 0);
    wt_kernel<<<256, 256, 0, stream>>>(Wr_ba0, WTba0, 256, 512, 256);
    wt_kernel<<<256, 256, 0, stream>>>(Wl_ab0, WTab0, 256, 512, 0);
    wt_kernel<<<256, 256, 0, stream>>>(Wr_ab0, WTab0, 256, 512, 256);
    wt_kernel<<<256, 256, 0, stream>>>(Wl_ba1, WTba1, 256, 512, 0);
    wt_kernel<<<256, 256, 0, stream>>>(Wr_ba1, WTba1, 256, 512, 256);
    wt_kernel<<<256, 256, 0, stream>>>(Wl_ab1, WTab1, 256, 512, 0);
    wt_kernel<<<256, 256, 0, stream>>>(Wr_ab1, WTab1, 256, 512, 256);

    // ---- input projections (bf16 out) ----
    gemm_mfma<0, 128, 0><<<gg, 256, 0, stream>>>(nullptr, xbA, linAT, nullptr, nullptr, projA, NN);
    gemm_mfma<0, 128, 0><<<gg, 256, 0, stream>>>(nullptr, xbB, linBT, nullptr, nullptr, projB, NN);

    // ---- layer 0 (fused gather+GEMM, both edge types in one dispatch) ----
    fused_sage<0><<<gF, 256, 0, stream>>>(rowptr2, ssrc2,
        projB, projA,          // gather sources (y=0: B->A, y=1: A->B)
        projA, projB,          // root features
        WTba0, WTab0, bl_ba0, bl_ab0, nullptr, nullptr, l0A, l0B);

    // ---- layer 1 (fused, fp32 + per-type bias + sigmoid into d_out) ----
    fused_sage<1><<<gF, 256, 0, stream>>>(rowptr2, ssrc2,
        l0B, l0A,
        l0A, l0B,
        WTba1, WTab1, bl_ba1, bl_ab1, bias_A, bias_B, gA, gB);
}